// Round 1
// baseline (205.247 us; speedup 1.0000x reference)
//
#include <hip/hip_runtime.h>
#include <hip/hip_cooperative_groups.h>

namespace cg = cooperative_groups;

typedef __attribute__((ext_vector_type(8))) short bf8;
typedef __attribute__((ext_vector_type(4))) float f4;

// ws layout (short-element offsets)
#define QBF  0         // q  bf16 [2048][256]
#define KBF  524288    // k  bf16 [2048][256]
#define REBF 1048576   // rel_emb bf16 [112][256], rows 99..111 zero

static __device__ __forceinline__ short bfr(float x) {
    union { float f; unsigned u; } v; v.f = x;
    return (short)((v.u + 0x7FFF + ((v.u >> 16) & 1)) >> 16);  // RNE
}
static __device__ __forceinline__ bf8 pack8(float4 a, float4 b) {
    bf8 r;
    r[0] = bfr(a.x); r[1] = bfr(a.y); r[2] = bfr(a.z); r[3] = bfr(a.w);
    r[4] = bfr(b.x); r[5] = bfr(b.y); r[6] = bfr(b.z); r[7] = bfr(b.w);
    return r;
}

// Fused kernel: 256 blocks x 512 threads, exactly co-resident (1 block/CU).
// Phase 0: rel_emb fp32->bf16 cast (first 1792 global threads) + projection
//   GEMMs. Block blk -> (mat = blk>>7, tile t = blk&127): 64x64 output tile,
//   8 waves = 4 row-strips x 2 col-halves (16x32 per wave).
// grid.sync()
// Phase 1: attention. Block = (b = blk>>6, 8-row i-tile i0 = (blk&63)*8),
//   identical structure to the previous attn_kernel (A-rows duplicated so the
//   16x16 MFMA tile carries 8 real rows; 3-barrier softmax — measured faster
//   than online recombine in the prior session).
__global__ __launch_bounds__(512) void fused_kernel(
    const float* __restrict__ queries, const float* __restrict__ keys,
    const float* __restrict__ bq, const float* __restrict__ bk,
    const float* __restrict__ Wq, const float* __restrict__ Wk,
    const float* __restrict__ rel_emb, const int* __restrict__ relations,
    short* __restrict__ ws, float* __restrict__ out)
{
    __shared__ union SM {
        short w_l[64 * 264];  // proj: bf16 W tile, row stride 264 (bank-tiled)
        struct {
            float qr_l[16][112];
            float red_m[16][8];
            float red_s[16][8];
        } a;                  // attn
    } sm;

    int blk = blockIdx.x;
    int tid = threadIdx.x;
    int w = tid >> 6;
    int lane = tid & 63;
    int n15 = lane & 15, quad = lane >> 4;

    // ---- Phase 0a: rel_emb cast: 1792 chunks x 16 shorts = 112*256 ----
    {
        int g = blk * 512 + tid;
        if (g < 1792) {
            int idx = g * 16;
            float4 a = make_float4(0.f, 0.f, 0.f, 0.f), b = a, c2 = a, d = a;
            if ((idx >> 8) < 99) {
                const float4* s = (const float4*)(rel_emb + idx);
                a = s[0]; b = s[1]; c2 = s[2]; d = s[3];
            }
            *(bf8*)(ws + REBF + idx) = pack8(a, b);
            *(bf8*)(ws + REBF + idx + 8) = pack8(c2, d);
        }
    }

    // ---- Phase 0b: projection GEMM ----
    {
        int mat = blk >> 7;          // 0 = q, 1 = k
        int t = blk & 127;           // 32 m-tiles x 4 n-tiles
        int m0 = (t >> 2) * 64;
        int n0 = (t & 3) * 64;
        const float* x = mat ? keys : queries;
        const float* W = mat ? Wk : Wq;
        const float* bias = mat ? bk : bq;
        short* outp = ws + (mat ? KBF : QBF);

        int wr = w & 3, wc = w >> 2;  // wave -> 16-row strip x 32-col half

        // stage W[n0..n0+64)[0..256) fp32 -> bf16 LDS (coalesced 32B/lane)
#pragma unroll
        for (int cc = 0; cc < 4; cc++) {
            int chunk = cc * 512 + tid;          // 2048 chunks of 8 floats
            int row = chunk >> 5, col8 = chunk & 31;
            const float4* s = (const float4*)(W + (n0 + row) * 256 + col8 * 8);
            *(bf8*)&sm.w_l[row * 264 + col8 * 8] = pack8(s[0], s[1]);
        }

        // A-frags: x rows m0 + wr*16 + n15, packed fp32->bf16
        int mrow = m0 + wr * 16 + n15;
        bf8 afr[8];
#pragma unroll
        for (int kk = 0; kk < 8; kk++) {
            const float4* ap = (const float4*)(x + mrow * 256 + kk * 32 + quad * 8);
            afr[kk] = pack8(ap[0], ap[1]);
        }
        __syncthreads();

        f4 z = {0.f, 0.f, 0.f, 0.f};
        f4 c[2] = {z, z};
#pragma unroll
        for (int nt = 0; nt < 2; nt++) {
            const short* wrp = &sm.w_l[(wc * 32 + nt * 16 + n15) * 264 + quad * 8];
#pragma unroll
            for (int kk = 0; kk < 8; kk++) {
                bf8 bfrag = *(const bf8*)(wrp + kk * 32);
                c[nt] = __builtin_amdgcn_mfma_f32_16x16x32_bf16(afr[kk], bfrag, c[nt], 0, 0, 0);
            }
        }

        int mbase = m0 + wr * 16 + quad * 4;
#pragma unroll
        for (int nt = 0; nt < 2; nt++) {
            int col = n0 + wc * 32 + nt * 16 + n15;
            float bv = bias[col];
#pragma unroll
            for (int reg = 0; reg < 4; reg++)
                outp[(mbase + reg) * 256 + col] = bfr(c[nt][reg] + bv);
        }
    }

    __threadfence();          // make ws writes device-visible
    cg::this_grid().sync();   // all proj/cast done before attention

    // ---- Phase 1: attention ----
    {
        int b = blk >> 6;
        int i0 = (blk & 63) * 8;
        int gi0 = b * 512 + i0;
        int j0 = w * 64;

        // prefetch relations: C row m=quad*4+reg -> real row (quad&1)*4+reg
        const int* rb = relations + (gi0 + (quad & 1) * 4) * 512 + j0 + n15;
        int rv[4][4];
#pragma unroll
        for (int reg = 0; reg < 4; reg++)
#pragma unroll
            for (int nt = 0; nt < 4; nt++)
                rv[nt][reg] = rb[reg * 512 + nt * 16];

        const short* qbf = ws + QBF;
        const short* kbf = ws + KBF;
        const short* rebf = ws + REBF;

        // A-frags: q row gi0 + (n15&7)  (rows 8..15 duplicate 0..7)
        int arow = gi0 + (n15 & 7);
        bf8 afr[8];
#pragma unroll
        for (int kk = 0; kk < 8; kk++)
            afr[kk] = *(const bf8*)(qbf + arow * 256 + kk * 32 + quad * 8);

        f4 z = {0.f, 0.f, 0.f, 0.f};
        f4 c[4] = {z, z, z, z};
#pragma unroll
        for (int nt = 0; nt < 4; nt++) {
            int krow = b * 512 + j0 + nt * 16 + n15;
            const short* kr = kbf + krow * 256 + quad * 8;
#pragma unroll
            for (int kk = 0; kk < 8; kk++) {
                bf8 bfrag = *(const bf8*)(kr + kk * 32);
                c[nt] = __builtin_amdgcn_mfma_f32_16x16x32_bf16(afr[kk], bfrag, c[nt], 0, 0, 0);
            }
        }

        if (w < 7) {  // qr tile: rel rows w*16..w*16+15 (rebf zero-padded to 112)
            f4 cq = z;
            const short* rr = rebf + (w * 16 + n15) * 256 + quad * 8;
#pragma unroll
            for (int kk = 0; kk < 8; kk++) {
                bf8 bfrag = *(const bf8*)(rr + kk * 32);
                cq = __builtin_amdgcn_mfma_f32_16x16x32_bf16(afr[kk], bfrag, cq, 0, 0, 0);
            }
#pragma unroll
            for (int reg = 0; reg < 4; reg++)
                sm.a.qr_l[quad * 4 + reg][w * 16 + n15] = cq[reg];  // dup rows dup values
        }
        __syncthreads();

        const float scale = 0.0625f;  // 1/sqrt(256)
        float lg[4][4];
#pragma unroll
        for (int nt = 0; nt < 4; nt++)
#pragma unroll
            for (int reg = 0; reg < 4; reg++)
                lg[nt][reg] = (c[nt][reg] + sm.a.qr_l[quad * 4 + reg][rv[nt][reg]]) * scale;

        float pm[4];
#pragma unroll
        for (int reg = 0; reg < 4; reg++) {
            float m = fmaxf(fmaxf(lg[0][reg], lg[1][reg]), fmaxf(lg[2][reg], lg[3][reg]));
#pragma unroll
            for (int d = 1; d <= 8; d <<= 1) m = fmaxf(m, __shfl_xor(m, d, 64));
            pm[reg] = m;
        }
        if (n15 == 0)
#pragma unroll
            for (int reg = 0; reg < 4; reg++) sm.a.red_m[quad * 4 + reg][w] = pm[reg];
        __syncthreads();
        float M[4];
#pragma unroll
        for (int reg = 0; reg < 4; reg++) {
            f4 a0 = *(const f4*)&sm.a.red_m[quad * 4 + reg][0];
            f4 a1 = *(const f4*)&sm.a.red_m[quad * 4 + reg][4];
            M[reg] = fmaxf(fmaxf(fmaxf(a0[0], a0[1]), fmaxf(a0[2], a0[3])),
                           fmaxf(fmaxf(a1[0], a1[1]), fmaxf(a1[2], a1[3])));
        }

        float ps[4];
#pragma unroll
        for (int reg = 0; reg < 4; reg++) {
            float s = 0.f;
#pragma unroll
            for (int nt = 0; nt < 4; nt++) {
                float e = __expf(lg[nt][reg] - M[reg]);
                lg[nt][reg] = e;
                s += e;
            }
#pragma unroll
            for (int d = 1; d <= 8; d <<= 1) s += __shfl_xor(s, d, 64);
            ps[reg] = s;
        }
        if (n15 == 0)
#pragma unroll
            for (int reg = 0; reg < 4; reg++) sm.a.red_s[quad * 4 + reg][w] = ps[reg];
        __syncthreads();
        float inv[4];
#pragma unroll
        for (int reg = 0; reg < 4; reg++) {
            f4 a0 = *(const f4*)&sm.a.red_s[quad * 4 + reg][0];
            f4 a1 = *(const f4*)&sm.a.red_s[quad * 4 + reg][4];
            inv[reg] = 1.f / (a0[0] + a0[1] + a0[2] + a0[3] + a1[0] + a1[1] + a1[2] + a1[3]);
        }

        if (quad < 2) {  // rows 0..7 real; quads 2,3 are duplicates
            float* ob = out + (gi0 + quad * 4) * 512 + j0 + n15;
#pragma unroll
            for (int reg = 0; reg < 4; reg++)
#pragma unroll
                for (int nt = 0; nt < 4; nt++)
                    ob[reg * 512 + nt * 16] = lg[nt][reg] * inv[reg];
        }
    }
}

extern "C" void kernel_launch(void* const* d_in, const int* in_sizes, int n_in,
                              void* d_out, int out_size, void* d_ws, size_t ws_size,
                              hipStream_t stream) {
    const float* queries = (const float*)d_in[0];
    const float* keys = (const float*)d_in[1];
    const int* relations = (const int*)d_in[2];
    const float* Wq = (const float*)d_in[3];
    const float* bq = (const float*)d_in[4];
    const float* Wk = (const float*)d_in[5];
    const float* bk = (const float*)d_in[6];
    const float* rel_emb = (const float*)d_in[7];
    short* wss = (short*)d_ws;
    float* out = (float*)d_out;

    void* args[] = {(void*)&queries, (void*)&keys, (void*)&bq, (void*)&bk,
                    (void*)&Wq, (void*)&Wk, (void*)&rel_emb, (void*)&relations,
                    (void*)&wss, (void*)&out};
    hipLaunchCooperativeKernel((void*)fused_kernel, dim3(256), dim3(512), args, 0, stream);
}

// Round 2
// 129.379 us; speedup vs baseline: 1.5864x; 1.5864x over previous
//
#include <hip/hip_runtime.h>

typedef __attribute__((ext_vector_type(8))) short bf8;
typedef __attribute__((ext_vector_type(4))) float f4;

// ws layout (short-element offsets)
#define QBF  0         // q  bf16 [2048][256]
#define KBF  524288    // k  bf16 [2048][256]
#define REBF 1048576   // rel_emb bf16 [112][256], rows 99..111 zero

static __device__ __forceinline__ short bfr(float x) {
    union { float f; unsigned u; } v; v.f = x;
    return (short)((v.u + 0x7FFF + ((v.u >> 16) & 1)) >> 16);  // RNE
}
static __device__ __forceinline__ bf8 pack8(float4 a, float4 b) {
    bf8 r;
    r[0] = bfr(a.x); r[1] = bfr(a.y); r[2] = bfr(a.z); r[3] = bfr(a.w);
    r[4] = bfr(b.x); r[5] = bfr(b.y); r[6] = bfr(b.z); r[7] = bfr(b.w);
    return r;
}

// K1: blocks 0..1023: proj GEMM tiles (M=32 x N=32, 4 waves of 16x16 each);
// blocks 1024..1030: rel_emb fp32->bf16 cast.
// Small tiles on purpose: 1024 blocks = 4 blocks/CU = 16 waves/CU (latency
// hiding; R0 ran 1 wave/SIMD and was latency-bound, all pipes <5%).
// out[row][col] = sum_h x[row][h]*W[col][h] + bias[col].
__global__ __launch_bounds__(256) void proj_kernel(const float* __restrict__ queries,
                                                   const float* __restrict__ keys,
                                                   const float* __restrict__ bq,
                                                   const float* __restrict__ bk,
                                                   const float* __restrict__ Wq,
                                                   const float* __restrict__ Wk,
                                                   const float* __restrict__ rel_emb,
                                                   short* __restrict__ ws) {
    __shared__ short w_l[32 * 264];  // bf16 W tile, row stride 264 shorts
    int blk = blockIdx.x;
    int tid = threadIdx.x;

    if (blk >= 1024) {
        // rel_emb cast: 7 blocks x 256 thr x 16 shorts = 28672 = 112*256
        int idx = ((blk - 1024) * 256 + tid) * 16;
        float4 a = make_float4(0.f, 0.f, 0.f, 0.f), b = a, c = a, d = a;
        if ((idx >> 8) < 99) {
            const float4* s = (const float4*)(rel_emb + idx);
            a = s[0]; b = s[1]; c = s[2]; d = s[3];
        }
        *(bf8*)(ws + REBF + idx) = pack8(a, b);
        *(bf8*)(ws + REBF + idx + 8) = pack8(c, d);
        return;
    }

    int mat = blk >> 9;          // 0 = q, 1 = k
    int t = blk & 511;           // 64 m-tiles x 8 n-tiles
    int m0 = (t >> 3) * 32;
    int n0 = (t & 7) * 32;
    const float* x = mat ? keys : queries;
    const float* W = mat ? Wk : Wq;
    const float* bias = mat ? bk : bq;
    short* outp = ws + (mat ? KBF : QBF);

    int w = tid >> 6;
    int lane = tid & 63;
    int n15 = lane & 15, quad = lane >> 4;
    int wr = w & 1, wc = w >> 1;  // wave -> 16-row strip x 16-col strip

    // stage W[n0..n0+32)[0..256) fp32 -> bf16 LDS (coalesced 32B/lane reads)
#pragma unroll
    for (int cc = 0; cc < 4; cc++) {
        int chunk = cc * 256 + tid;          // 1024 chunks of 8 floats
        int row = chunk >> 5, col8 = chunk & 31;
        const float4* s = (const float4*)(W + (n0 + row) * 256 + col8 * 8);
        *(bf8*)&w_l[row * 264 + col8 * 8] = pack8(s[0], s[1]);
    }

    // A-frags: x rows m0 + wr*16 + n15, packed fp32->bf16
    int mrow = m0 + wr * 16 + n15;
    bf8 afr[8];
#pragma unroll
    for (int kk = 0; kk < 8; kk++) {
        const float4* ap = (const float4*)(x + mrow * 256 + kk * 32 + quad * 8);
        afr[kk] = pack8(ap[0], ap[1]);
    }
    __syncthreads();

    f4 c = {0.f, 0.f, 0.f, 0.f};
    const short* wrp = &w_l[(wc * 16 + n15) * 264 + quad * 8];
#pragma unroll
    for (int kk = 0; kk < 8; kk++) {
        bf8 bfrag = *(const bf8*)(wrp + kk * 32);
        c = __builtin_amdgcn_mfma_f32_16x16x32_bf16(afr[kk], bfrag, c, 0, 0, 0);
    }

    int mbase = m0 + wr * 16 + quad * 4;
    int col = n0 + wc * 16 + n15;
    float bv = bias[col];
#pragma unroll
    for (int reg = 0; reg < 4; reg++)
        outp[(mbase + reg) * 256 + col] = bfr(c[reg] + bv);
}

// K2: fused qk + qr + softmax. Block = (b, 4-row i-tile): grid 512 x 512 thr
// (2 blocks/CU, 16 waves/CU). A-rows duplicated 4x (row = n15&3) so the 16x16
// MFMA tile carries 4 real rows; dup lanes hit identical cache lines.
// 3-barrier softmax (measured faster than online recombine in prior session).
// Duplicate quads each store a different nt chunk -> fully-coalesced output.
__global__ __launch_bounds__(512) void attn_kernel(const int* __restrict__ relations,
                                                   const short* __restrict__ ws,
                                                   float* __restrict__ out) {
    __shared__ float qr_l[16][112];
    __shared__ float red_m[16][8];
    __shared__ float red_s[16][8];

    int blk = blockIdx.x;
    int b = blk >> 7;
    int i0 = (blk & 127) * 4;
    int gi0 = b * 512 + i0;
    int w = threadIdx.x >> 6;
    int lane = threadIdx.x & 63;
    int n15 = lane & 15, quad = lane >> 4;
    int j0 = w * 64;

    // prefetch relations: C row quad*4+reg holds q-row reg (4x dup over quads)
    const int* rb = relations + gi0 * 512 + j0 + n15;
    int rv[4][4];
#pragma unroll
    for (int reg = 0; reg < 4; reg++)
#pragma unroll
        for (int nt = 0; nt < 4; nt++)
            rv[nt][reg] = rb[reg * 512 + nt * 16];

    const short* qbf = ws + QBF;
    const short* kbf = ws + KBF;
    const short* rebf = ws + REBF;

    // A-frags: q row gi0 + (n15&3)  (rows 4..15 duplicate 0..3)
    int arow = gi0 + (n15 & 3);
    bf8 afr[8];
#pragma unroll
    for (int kk = 0; kk < 8; kk++)
        afr[kk] = *(const bf8*)(qbf + arow * 256 + kk * 32 + quad * 8);

    f4 z = {0.f, 0.f, 0.f, 0.f};
    f4 c[4] = {z, z, z, z};
#pragma unroll
    for (int nt = 0; nt < 4; nt++) {
        int krow = b * 512 + j0 + nt * 16 + n15;
        const short* kr = kbf + krow * 256 + quad * 8;
#pragma unroll
        for (int kk = 0; kk < 8; kk++) {
            bf8 bfrag = *(const bf8*)(kr + kk * 32);
            c[nt] = __builtin_amdgcn_mfma_f32_16x16x32_bf16(afr[kk], bfrag, c[nt], 0, 0, 0);
        }
    }

    if (w < 7) {  // qr tile: rel rows w*16..w*16+15 (rebf zero-padded to 112)
        f4 cq = z;
        const short* rr = rebf + (w * 16 + n15) * 256 + quad * 8;
#pragma unroll
        for (int kk = 0; kk < 8; kk++) {
            bf8 bfrag = *(const bf8*)(rr + kk * 32);
            cq = __builtin_amdgcn_mfma_f32_16x16x32_bf16(afr[kk], bfrag, cq, 0, 0, 0);
        }
#pragma unroll
        for (int reg = 0; reg < 4; reg++)
            qr_l[quad * 4 + reg][w * 16 + n15] = cq[reg];  // dup rows get dup values
    }
    __syncthreads();

    const float scale = 0.0625f;  // 1/sqrt(256)
    float lg[4][4];
#pragma unroll
    for (int nt = 0; nt < 4; nt++)
#pragma unroll
        for (int reg = 0; reg < 4; reg++)
            lg[nt][reg] = (c[nt][reg] + qr_l[quad * 4 + reg][rv[nt][reg]]) * scale;

    float pm[4];
#pragma unroll
    for (int reg = 0; reg < 4; reg++) {
        float m = fmaxf(fmaxf(lg[0][reg], lg[1][reg]), fmaxf(lg[2][reg], lg[3][reg]));
#pragma unroll
        for (int d = 1; d <= 8; d <<= 1) m = fmaxf(m, __shfl_xor(m, d, 64));
        pm[reg] = m;
    }
    if (n15 == 0)
#pragma unroll
        for (int reg = 0; reg < 4; reg++) red_m[quad * 4 + reg][w] = pm[reg];
    __syncthreads();
    float M[4];
#pragma unroll
    for (int reg = 0; reg < 4; reg++) {
        f4 a0 = *(const f4*)&red_m[quad * 4 + reg][0];
        f4 a1 = *(const f4*)&red_m[quad * 4 + reg][4];
        M[reg] = fmaxf(fmaxf(fmaxf(a0[0], a0[1]), fmaxf(a0[2], a0[3])),
                       fmaxf(fmaxf(a1[0], a1[1]), fmaxf(a1[2], a1[3])));
    }

    float ps[4];
#pragma unroll
    for (int reg = 0; reg < 4; reg++) {
        float s = 0.f;
#pragma unroll
        for (int nt = 0; nt < 4; nt++) {
            float e = __expf(lg[nt][reg] - M[reg]);
            lg[nt][reg] = e;
            s += e;
        }
#pragma unroll
        for (int d = 1; d <= 8; d <<= 1) s += __shfl_xor(s, d, 64);
        ps[reg] = s;
    }
    if (n15 == 0)
#pragma unroll
        for (int reg = 0; reg < 4; reg++) red_s[quad * 4 + reg][w] = ps[reg];
    __syncthreads();
    float inv[4];
#pragma unroll
    for (int reg = 0; reg < 4; reg++) {
        f4 a0 = *(const f4*)&red_s[quad * 4 + reg][0];
        f4 a1 = *(const f4*)&red_s[quad * 4 + reg][4];
        inv[reg] = 1.f / (a0[0] + a0[1] + a0[2] + a0[3] + a1[0] + a1[1] + a1[2] + a1[3]);
    }

    // all 4 quads hold identical values; quad q stores nt=q chunk ->
    // 64 consecutive floats per wave per reg (fully coalesced).
    float sv[4];
#pragma unroll
    for (int reg = 0; reg < 4; reg++) {
        float v = lg[0][reg];
        if (quad == 1) v = lg[1][reg];
        if (quad == 2) v = lg[2][reg];
        if (quad == 3) v = lg[3][reg];
        sv[reg] = v * inv[reg];
    }
    float* ob = out + gi0 * 512 + j0 + quad * 16 + n15;
#pragma unroll
    for (int reg = 0; reg < 4; reg++)
        ob[reg * 512] = sv[reg];
}

extern "C" void kernel_launch(void* const* d_in, const int* in_sizes, int n_in,
                              void* d_out, int out_size, void* d_ws, size_t ws_size,
                              hipStream_t stream) {
    const float* queries = (const float*)d_in[0];
    const float* keys = (const float*)d_in[1];
    const int* relations = (const int*)d_in[2];
    const float* Wq = (const float*)d_in[3];
    const float* bq = (const float*)d_in[4];
    const float* Wk = (const float*)d_in[5];
    const float* bk = (const float*)d_in[6];
    const float* rel_emb = (const float*)d_in[7];
    short* wss = (short*)d_ws;
    float* out = (float*)d_out;

    hipLaunchKernelGGL(proj_kernel, dim3(1031), dim3(256), 0, stream,
                       queries, keys, bq, bk, Wq, Wk, rel_emb, wss);
    hipLaunchKernelGGL(attn_kernel, dim3(512), dim3(512), 0, stream, relations, wss, out);
}

// Round 3
// 93.567 us; speedup vs baseline: 2.1936x; 1.3827x over previous
//
#include <hip/hip_runtime.h>

typedef __attribute__((ext_vector_type(8))) short bf8;
typedef __attribute__((ext_vector_type(4))) float f4;

// ws layout (short-element offsets)
#define QBF  0         // q  bf16 [2048][256]
#define KBF  524288    // k  bf16 [2048][256]
#define REBF 1048576   // rel_emb bf16 [112][256], rows 99..111 zero

static __device__ __forceinline__ short bfr(float x) {
    union { float f; unsigned u; } v; v.f = x;
    return (short)((v.u + 0x7FFF + ((v.u >> 16) & 1)) >> 16);  // RNE
}
static __device__ __forceinline__ bf8 pack8(float4 a, float4 b) {
    bf8 r;
    r[0] = bfr(a.x); r[1] = bfr(a.y); r[2] = bfr(a.z); r[3] = bfr(a.w);
    r[4] = bfr(b.x); r[5] = bfr(b.y); r[6] = bfr(b.z); r[7] = bfr(b.w);
    return r;
}

// K1: blocks 0..255: proj GEMM tiles (M=64 x N=64) with 512 threads = 8 waves
// (wave (wr,wc) computes a 16x32 sub-tile). Same tile size / same traffic as
// the 4-wave R0 version but 2 waves/SIMD instead of 1 -> latency overlap.
// Blocks 256..259: rel_emb fp32->bf16 cast.
// out[row][col] = sum_h x[row][h]*W[col][h] + bias[col].
__global__ __launch_bounds__(512) void proj_kernel(const float* __restrict__ queries,
                                                   const float* __restrict__ keys,
                                                   const float* __restrict__ bq,
                                                   const float* __restrict__ bk,
                                                   const float* __restrict__ Wq,
                                                   const float* __restrict__ Wk,
                                                   const float* __restrict__ rel_emb,
                                                   short* __restrict__ ws) {
    __shared__ short w_l[64 * 264];  // bf16 W tile, row stride 264 shorts
    int blk = blockIdx.x;
    int tid = threadIdx.x;

    if (blk >= 256) {
        // rel_emb cast: 4 blocks x 512 thr; 1792 chunks x 16 shorts = 112*256
        int g = (blk - 256) * 512 + tid;
        if (g < 1792) {
            int idx = g * 16;
            float4 a = make_float4(0.f, 0.f, 0.f, 0.f), b = a, c = a, d = a;
            if ((idx >> 8) < 99) {
                const float4* s = (const float4*)(rel_emb + idx);
                a = s[0]; b = s[1]; c = s[2]; d = s[3];
            }
            *(bf8*)(ws + REBF + idx) = pack8(a, b);
            *(bf8*)(ws + REBF + idx + 8) = pack8(c, d);
        }
        return;
    }

    int mat = blk >> 7;          // 0 = q, 1 = k
    int t = blk & 127;           // 32 m-tiles x 4 n-tiles
    int m0 = (t >> 2) * 64;
    int n0 = (t & 3) * 64;
    const float* x = mat ? keys : queries;
    const float* W = mat ? Wk : Wq;
    const float* bias = mat ? bk : bq;
    short* outp = ws + (mat ? KBF : QBF);

    int w = tid >> 6;
    int lane = tid & 63;
    int n15 = lane & 15, quad = lane >> 4;
    int wr = w & 3, wc = w >> 2;  // wave -> 16-row strip x 32-col half

    // stage W[n0..n0+64)[0..256) fp32 -> bf16 LDS (coalesced 32B/lane reads)
#pragma unroll
    for (int cc = 0; cc < 4; cc++) {
        int chunk = cc * 512 + tid;          // 2048 chunks of 8 floats
        int row = chunk >> 5, col8 = chunk & 31;
        const float4* s = (const float4*)(W + (n0 + row) * 256 + col8 * 8);
        *(bf8*)&w_l[row * 264 + col8 * 8] = pack8(s[0], s[1]);
    }

    // A-frags: x rows m0 + wr*16 + n15, packed fp32->bf16
    int mrow = m0 + wr * 16 + n15;
    bf8 afr[8];
#pragma unroll
    for (int kk = 0; kk < 8; kk++) {
        const float4* ap = (const float4*)(x + mrow * 256 + kk * 32 + quad * 8);
        afr[kk] = pack8(ap[0], ap[1]);
    }
    __syncthreads();

    f4 z = {0.f, 0.f, 0.f, 0.f};
    f4 c[2] = {z, z};
#pragma unroll
    for (int nt = 0; nt < 2; nt++) {
        const short* wrp = &w_l[(wc * 32 + nt * 16 + n15) * 264 + quad * 8];
#pragma unroll
        for (int kk = 0; kk < 8; kk++) {
            bf8 bfrag = *(const bf8*)(wrp + kk * 32);
            c[nt] = __builtin_amdgcn_mfma_f32_16x16x32_bf16(afr[kk], bfrag, c[nt], 0, 0, 0);
        }
    }

    int mbase = m0 + wr * 16 + quad * 4;
#pragma unroll
    for (int nt = 0; nt < 2; nt++) {
        int col = n0 + wc * 32 + nt * 16 + n15;
        float bv = bias[col];
#pragma unroll
        for (int reg = 0; reg < 4; reg++)
            outp[(mbase + reg) * 256 + col] = bfr(c[nt][reg] + bv);
    }
}

// K2: fused qk + qr + softmax — R0-exact structure (measured best: ~18 us).
// Block = (b, 8-row i-tile): grid 256 x 512 thr. A-rows duplicated (row =
// n15&7) so the 16x16 MFMA tile carries 8 real rows; dup lanes hit identical
// cache lines (L1/L2-absorbed). 3-barrier softmax (measured faster than online
// recombine: R8 91.1 vs R10 94.4 in prior session). Do NOT shrink the i-tile:
// 4-row tiles doubled K L2 traffic and tripled this kernel (R2: 52 us).
__global__ __launch_bounds__(512) void attn_kernel(const int* __restrict__ relations,
                                                   const short* __restrict__ ws,
                                                   float* __restrict__ out) {
    __shared__ float qr_l[16][112];
    __shared__ float red_m[16][8];
    __shared__ float red_s[16][8];

    int blk = blockIdx.x;
    int b = blk >> 6;
    int i0 = (blk & 63) * 8;
    int gi0 = b * 512 + i0;
    int w = threadIdx.x >> 6;
    int lane = threadIdx.x & 63;
    int n15 = lane & 15, quad = lane >> 4;
    int j0 = w * 64;

    // prefetch relations: C row m=quad*4+reg -> real row (quad&1)*4+reg
    const int* rb = relations + (gi0 + (quad & 1) * 4) * 512 + j0 + n15;
    int rv[4][4];
#pragma unroll
    for (int reg = 0; reg < 4; reg++)
#pragma unroll
        for (int nt = 0; nt < 4; nt++)
            rv[nt][reg] = rb[reg * 512 + nt * 16];

    const short* qbf = ws + QBF;
    const short* kbf = ws + KBF;
    const short* rebf = ws + REBF;

    // A-frags: q row gi0 + (n15&7)  (rows 8..15 duplicate 0..7)
    int arow = gi0 + (n15 & 7);
    bf8 afr[8];
#pragma unroll
    for (int kk = 0; kk < 8; kk++)
        afr[kk] = *(const bf8*)(qbf + arow * 256 + kk * 32 + quad * 8);

    f4 z = {0.f, 0.f, 0.f, 0.f};
    f4 c[4] = {z, z, z, z};
#pragma unroll
    for (int nt = 0; nt < 4; nt++) {
        int krow = b * 512 + j0 + nt * 16 + n15;
        const short* kr = kbf + krow * 256 + quad * 8;
#pragma unroll
        for (int kk = 0; kk < 8; kk++) {
            bf8 bfrag = *(const bf8*)(kr + kk * 32);
            c[nt] = __builtin_amdgcn_mfma_f32_16x16x32_bf16(afr[kk], bfrag, c[nt], 0, 0, 0);
        }
    }

    if (w < 7) {  // qr tile: rel rows w*16..w*16+15 (rebf zero-padded to 112)
        f4 cq = z;
        const short* rr = rebf + (w * 16 + n15) * 256 + quad * 8;
#pragma unroll
        for (int kk = 0; kk < 8; kk++) {
            bf8 bfrag = *(const bf8*)(rr + kk * 32);
            cq = __builtin_amdgcn_mfma_f32_16x16x32_bf16(afr[kk], bfrag, cq, 0, 0, 0);
        }
#pragma unroll
        for (int reg = 0; reg < 4; reg++)
            qr_l[quad * 4 + reg][w * 16 + n15] = cq[reg];  // dup rows get dup values
    }
    __syncthreads();

    const float scale = 0.0625f;  // 1/sqrt(256)
    float lg[4][4];
#pragma unroll
    for (int nt = 0; nt < 4; nt++)
#pragma unroll
        for (int reg = 0; reg < 4; reg++)
            lg[nt][reg] = (c[nt][reg] + qr_l[quad * 4 + reg][rv[nt][reg]]) * scale;

    float pm[4];
#pragma unroll
    for (int reg = 0; reg < 4; reg++) {
        float m = fmaxf(fmaxf(lg[0][reg], lg[1][reg]), fmaxf(lg[2][reg], lg[3][reg]));
#pragma unroll
        for (int d = 1; d <= 8; d <<= 1) m = fmaxf(m, __shfl_xor(m, d, 64));
        pm[reg] = m;
    }
    if (n15 == 0)
#pragma unroll
        for (int reg = 0; reg < 4; reg++) red_m[quad * 4 + reg][w] = pm[reg];
    __syncthreads();
    float M[4];
#pragma unroll
    for (int reg = 0; reg < 4; reg++) {
        f4 a0 = *(const f4*)&red_m[quad * 4 + reg][0];
        f4 a1 = *(const f4*)&red_m[quad * 4 + reg][4];
        M[reg] = fmaxf(fmaxf(fmaxf(a0[0], a0[1]), fmaxf(a0[2], a0[3])),
                       fmaxf(fmaxf(a1[0], a1[1]), fmaxf(a1[2], a1[3])));
    }

    float ps[4];
#pragma unroll
    for (int reg = 0; reg < 4; reg++) {
        float s = 0.f;
#pragma unroll
        for (int nt = 0; nt < 4; nt++) {
            float e = __expf(lg[nt][reg] - M[reg]);
            lg[nt][reg] = e;
            s += e;
        }
#pragma unroll
        for (int d = 1; d <= 8; d <<= 1) s += __shfl_xor(s, d, 64);
        ps[reg] = s;
    }
    if (n15 == 0)
#pragma unroll
        for (int reg = 0; reg < 4; reg++) red_s[quad * 4 + reg][w] = ps[reg];
    __syncthreads();
    float inv[4];
#pragma unroll
    for (int reg = 0; reg < 4; reg++) {
        f4 a0 = *(const f4*)&red_s[quad * 4 + reg][0];
        f4 a1 = *(const f4*)&red_s[quad * 4 + reg][4];
        inv[reg] = 1.f / (a0[0] + a0[1] + a0[2] + a0[3] + a1[0] + a1[1] + a1[2] + a1[3]);
    }

    if (quad < 2) {  // rows 0..7 real; quads 2,3 are duplicates
        float* ob = out + (gi0 + quad * 4) * 512 + j0 + n15;
#pragma unroll
        for (int reg = 0; reg < 4; reg++)
#pragma unroll
            for (int nt = 0; nt < 4; nt++)
                ob[reg * 512 + nt * 16] = lg[nt][reg] * inv[reg];
    }
}

extern "C" void kernel_launch(void* const* d_in, const int* in_sizes, int n_in,
                              void* d_out, int out_size, void* d_ws, size_t ws_size,
                              hipStream_t stream) {
    const float* queries = (const float*)d_in[0];
    const float* keys = (const float*)d_in[1];
    const int* relations = (const int*)d_in[2];
    const float* Wq = (const float*)d_in[3];
    const float* bq = (const float*)d_in[4];
    const float* Wk = (const float*)d_in[5];
    const float* bk = (const float*)d_in[6];
    const float* rel_emb = (const float*)d_in[7];
    short* wss = (short*)d_ws;
    float* out = (float*)d_out;

    hipLaunchKernelGGL(proj_kernel, dim3(260), dim3(512), 0, stream,
                       queries, keys, bq, bk, Wq, Wk, rel_emb, wss);
    hipLaunchKernelGGL(attn_kernel, dim3(256), dim3(512), 0, stream, relations, wss, out);
}